// Round 1
// baseline (750.962 us; speedup 1.0000x reference)
//
#include <hip/hip_runtime.h>
#include <math.h>

#define TSEQ 2048
#define DM   768
#define NH   12
#define HD   64
#define NBH  24

// round(linspace(0, 2047, 32)) — verified against fp32 evaluation (no .5 ties)
__constant__ int c_idxp[32] = {0,66,132,198,264,330,396,462,528,594,660,726,
  792,858,924,990,1057,1123,1189,1255,1321,1387,1453,1519,1585,1651,1717,1783,
  1849,1915,1981,2047};

__device__ __forceinline__ float wsum(float v) {
#pragma unroll
  for (int m = 1; m < 64; m <<= 1) v += __shfl_xor(v, m, 64);
  return v;
}
__device__ __forceinline__ float wmaxr(float v) {
#pragma unroll
  for (int m = 1; m < 64; m <<= 1) v = fmaxf(v, __shfl_xor(v, m, 64));
  return v;
}

// ---------------- GEMM: dst = (X @ W^T + bias) * scale ----------------
// BM=BN=128, BK=16, 512 threads, 8x4 per thread.
// MODE 0: row-major [M,DM] store.  MODE 1: qkv layout store (b*NH+h, t, dd).
template <int MODE>
__device__ __forceinline__ void gemm_body(const float* __restrict__ X,
                                          const float* __restrict__ W,
                                          const float* __restrict__ bias,
                                          float* __restrict__ dst, float scale,
                                          int mblk, int nblk,
                                          float (*As)[132], float (*Bs)[132]) {
  const int tid = threadIdx.x;
  const int tx = tid & 31;       // column group (col = tx*4)
  const int ty = tid >> 5;       // 0..15 (rows ty*4+i and 64+ty*4+i)
  const int lr = tid >> 2;       // staging row 0..127
  const int lc = (tid & 3) * 4;  // staging k offset {0,4,8,12}
  const float* Xp = X + (size_t)(mblk + lr) * DM + lc;
  const float* Wp = W + (size_t)(nblk + lr) * DM + lc;
  float acc[2][4][4] = {};
  for (int k0 = 0; k0 < DM; k0 += 16) {
    float4 a = *(const float4*)(Xp + k0);
    float4 b = *(const float4*)(Wp + k0);
    __syncthreads();
    As[lc + 0][lr] = a.x; As[lc + 1][lr] = a.y; As[lc + 2][lr] = a.z; As[lc + 3][lr] = a.w;
    Bs[lc + 0][lr] = b.x; Bs[lc + 1][lr] = b.y; Bs[lc + 2][lr] = b.z; Bs[lc + 3][lr] = b.w;
    __syncthreads();
#pragma unroll
    for (int kk = 0; kk < 16; ++kk) {
      float4 a0 = *(const float4*)&As[kk][ty * 4];
      float4 a1 = *(const float4*)&As[kk][ty * 4 + 64];
      float4 bb = *(const float4*)&Bs[kk][tx * 4];
      float ar[2][4] = {{a0.x, a0.y, a0.z, a0.w}, {a1.x, a1.y, a1.z, a1.w}};
      float br[4] = {bb.x, bb.y, bb.z, bb.w};
#pragma unroll
      for (int im = 0; im < 2; ++im)
#pragma unroll
        for (int i = 0; i < 4; ++i)
#pragma unroll
          for (int j = 0; j < 4; ++j)
            acc[im][i][j] = fmaf(ar[im][i], br[j], acc[im][i][j]);
    }
  }
  const int col = nblk + tx * 4;
  const float b0 = bias[col + 0], b1 = bias[col + 1];
  const float b2 = bias[col + 2], b3 = bias[col + 3];
#pragma unroll
  for (int im = 0; im < 2; ++im) {
#pragma unroll
    for (int i = 0; i < 4; ++i) {
      int row = mblk + im * 64 + ty * 4 + i;
      float4 o;
      o.x = (acc[im][i][0] + b0) * scale;
      o.y = (acc[im][i][1] + b1) * scale;
      o.z = (acc[im][i][2] + b2) * scale;
      o.w = (acc[im][i][3] + b3) * scale;
      if (MODE == 0) {
        *(float4*)&dst[(size_t)row * DM + col] = o;
      } else {
        int b_ = row >> 11, t = row & (TSEQ - 1);
        int h = col >> 6, dd = col & 63;
        *(float4*)&dst[(((size_t)(b_ * NH + h)) * TSEQ + t) * HD + dd] = o;
      }
    }
  }
}

__global__ __launch_bounds__(512) void qkv_kernel(
    const float* __restrict__ X,
    const float* __restrict__ Wq, const float* __restrict__ bq, float* __restrict__ qd,
    const float* __restrict__ Wk, const float* __restrict__ bk, float* __restrict__ kd,
    const float* __restrict__ Wv, const float* __restrict__ bv, float* __restrict__ vd) {
  __shared__ float As[16][132];
  __shared__ float Bs[16][132];
  int z = blockIdx.z;
  const float* W = (z == 0) ? Wq : (z == 1) ? Wk : Wv;
  const float* bias = (z == 0) ? bq : (z == 1) ? bk : bv;
  float* dst = (z == 0) ? qd : (z == 1) ? kd : vd;
  float scale = (z == 0) ? 0.125f : 1.0f;
  gemm_body<1>(X, W, bias, dst, scale, blockIdx.y * 128, blockIdx.x * 128, As, Bs);
}

__global__ __launch_bounds__(512) void oproj_kernel(
    const float* __restrict__ X, const float* __restrict__ W,
    const float* __restrict__ bias, float* __restrict__ dst) {
  __shared__ float As[16][132];
  __shared__ float Bs[16][132];
  gemm_body<0>(X, W, bias, dst, 1.0f, blockIdx.y * 128, blockIdx.x * 128, As, Bs);
}

// ---------------- window selection: one wave per (bh, t) ----------------
__global__ __launch_bounds__(256) void window_kernel(
    const float* __restrict__ q, const float* __restrict__ k,
    int* __restrict__ sel) {
  int wid = blockIdx.x * 4 + (threadIdx.x >> 6);
  int lane = threadIdx.x & 63;
  int bh = wid >> 11, t = wid & (TSEQ - 1);
  int start = t - 8;
  if (start < 0) start = 0;
  if (start > TSEQ - 16) start = TSEQ - 16;
  const float* kp = k + ((size_t)bh * TSEQ + start) * HD + lane;
  float qv = q[((size_t)bh * TSEQ + t) * HD + lane];
  float kn[16], tmp[16];
#pragma unroll
  for (int f = 0; f < 16; ++f) {
    float kv = kp[f * HD];
    float n2 = wsum(kv * kv);
    float nrm = fmaxf(sqrtf(n2), 1e-6f);
    float s = wsum(qv * kv);
    int dist = start + f - t; if (dist < 0) dist = -dist;
    tmp[f] = s + 0.2f * expf(-(float)dist * 0.125f);
    kn[f] = kv / nrm;  // match reference: kw / max(norm, eps)
  }
  int* selp = sel + ((size_t)bh * TSEQ + t) * 6;
#pragma unroll
  for (int r = 0; r < 6; ++r) {
    float best = tmp[0]; int bj = 0;
#pragma unroll
    for (int f = 1; f < 16; ++f)
      if (tmp[f] > best) { best = tmp[f]; bj = f; }  // first-max, as jnp.argmax
    if (lane == 0) selp[r] = start + bj;
    if (r < 5) {
      float kj = 0.f;
#pragma unroll
      for (int f = 0; f < 16; ++f) kj = (f == bj) ? kn[f] : kj;
#pragma unroll
      for (int f = 0; f < 16; ++f) {
        float c = wsum(kn[f] * kj);
        c = fmaxf(c, 0.f);
        tmp[f] -= 0.2f * c;
      }
    }
#pragma unroll
    for (int f = 0; f < 16; ++f) tmp[f] = (f == bj) ? -1e9f : tmp[f];
  }
}

// ---------------- prototype queries Qp[a][p][:] ----------------
__global__ __launch_bounds__(256) void qp_kernel(const float* __restrict__ q,
                                                 float* __restrict__ Qp) {
  int wid = blockIdx.x * 4 + (threadIdx.x >> 6);  // 0..383
  int lane = threadIdx.x & 63;
  int a = wid >> 5, p = wid & 31;
  int t = c_idxp[p];
  float v = 0.5f * (q[((size_t)(2 * a) * TSEQ + t) * HD + lane] +
                    q[((size_t)(2 * a + 1) * TSEQ + t) * HD + lane]);
  float n2 = wsum(v * v);
  float nrm = fmaxf(sqrtf(n2), 1e-6f);
  Qp[((size_t)a * 32 + p) * HD + lane] = v / nrm;
}

// ---------------- S[a][t][p] and u[a][t] ----------------
__global__ __launch_bounds__(256) void proto_score_kernel(
    const float* __restrict__ k, const float* __restrict__ Qp,
    float* __restrict__ S, float* __restrict__ u) {
  int a = blockIdx.y;
  __shared__ float Qs[2048];
  for (int i = threadIdx.x; i < 2048; i += 256) Qs[i] = Qp[(size_t)a * 2048 + i];
  __syncthreads();
  int w = threadIdx.x >> 6, lane = threadIdx.x & 63;
  int t = blockIdx.x * 4 + w;
  float km = 0.5f * (k[((size_t)(2 * a) * TSEQ + t) * HD + lane] +
                     k[((size_t)(2 * a + 1) * TSEQ + t) * HD + lane]);
  float n2 = wsum(km * km);
  float nrm = fmaxf(sqrtf(n2), 1e-6f);
  float kb = km / nrm;
  float sval = 0.f;
#pragma unroll
  for (int p = 0; p < 32; ++p) {
    float dg = wsum(kb * Qs[p * 64 + lane]);
    dg = fmaxf(dg, 0.f);               // relu
    sval = (lane == p) ? dg : sval;    // lane p keeps S_p
  }
  if (lane < 32) S[((size_t)a * TSEQ + t) * 32 + lane] = sval;
  float x = (lane < 32) ? sval : 0.f;
  float mean = wsum(x) / 32.0f;
  float mx = wmaxr((lane < 32) ? sval : -1e30f);
  float cur = (lane < 32) ? sval : -1e30f;
  float topsum = 0.f;
#pragma unroll
  for (int r = 0; r < 6; ++r) {        // top-6 values (remove one instance each)
    float m = wmaxr(cur);
    topsum += m;
    unsigned long long ball = __ballot(cur == m);
    int first = __ffsll(ball) - 1;
    if (lane == first) cur = -1e30f;
  }
  float dev = (lane < 32) ? (sval - mean) : 0.f;
  float sd = sqrtf(wsum(dev * dev) / 31.0f);  // ddof=1
  float uval = ((1.0f * mean + 0.6f * mx) + 0.4f * (topsum / 6.0f)) + 0.2f * sd;
  if (lane == 0) u[(size_t)a * TSEQ + t] = uval;
}

// ---------------- per-head top-12 + greedy facility location ----------------
__global__ void head_select_kernel(const float* __restrict__ u,
                                   const float* __restrict__ S,
                                   int* __restrict__ glob) {
  int a = blockIdx.x;
  int lane = threadIdx.x;  // 64 threads
  float uv[32];
#pragma unroll
  for (int c = 0; c < 32; ++c) uv[c] = u[(size_t)a * TSEQ + c * 64 + lane];
  unsigned removed = 0;
  int tidx = 0;
#pragma unroll
  for (int r = 0; r < 12; ++r) {
    float best = -1e30f; int bidx = 1 << 30;
#pragma unroll
    for (int c = 0; c < 32; ++c) {
      if (!((removed >> c) & 1u)) {
        float vv = uv[c]; int gi = c * 64 + lane;
        if (vv > best || (vv == best && gi < bidx)) { best = vv; bidx = gi; }
      }
    }
#pragma unroll
    for (int mS = 1; mS < 64; mS <<= 1) {
      float ov = __shfl_xor(best, mS, 64);
      int oi = __shfl_xor(bidx, mS, 64);
      if (ov > best || (ov == best && oi < bidx)) { best = ov; bidx = oi; }
    }
    if (lane == (bidx & 63)) removed |= 1u << (bidx >> 6);
    if (lane == r) tidx = bidx;   // lane r remembers top_idx[r]
  }
  float srow[12];
#pragma unroll
  for (int r = 0; r < 12; ++r) {
    int tr = __shfl(tidx, r, 64);
    srow[r] = (lane < 32) ? S[((size_t)a * TSEQ + tr) * 32 + lane] : 0.f;
  }
  float m = 0.f;
  unsigned blocked = 0;
#pragma unroll
  for (int g = 0; g < 4; ++g) {
    float gains[12];
#pragma unroll
    for (int r = 0; r < 12; ++r) {
      float gr = (lane < 32) ? fmaxf(srow[r] - m, 0.f) : 0.f;
      gains[r] = wsum(gr);
    }
    float best = -1e30f; int bj = 0;
#pragma unroll
    for (int r = 0; r < 12; ++r) {
      float vv = ((blocked >> r) & 1u) ? -1e9f : gains[r];
      if (vv > best) { best = vv; bj = r; }  // first-max
    }
    blocked |= 1u << bj;
#pragma unroll
    for (int r = 0; r < 12; ++r) m = (r == bj) ? fmaxf(m, srow[r]) : m;
    int gidx = __shfl(tidx, bj, 64);
    if (lane == 0) glob[a * 4 + g] = gidx;
  }
}

// ---------------- final 10-candidate attention ----------------
__global__ __launch_bounds__(256) void attend_kernel(
    const float* __restrict__ q, const float* __restrict__ k,
    const float* __restrict__ v, const int* __restrict__ sel,
    const int* __restrict__ glob, float* __restrict__ preout) {
  int wid = blockIdx.x * 4 + (threadIdx.x >> 6);
  int lane = threadIdx.x & 63;
  int bh = wid >> 11, t = wid & (TSEQ - 1);
  int h = bh % NH, b = bh / NH;
  float qv = q[((size_t)bh * TSEQ + t) * HD + lane];
  int cand[10];
  const int* selp = sel + ((size_t)bh * TSEQ + t) * 6;
#pragma unroll
  for (int c = 0; c < 6; ++c) cand[c] = selp[c];
#pragma unroll
  for (int c = 0; c < 4; ++c) cand[6 + c] = glob[h * 4 + c];
  float sc[10];
#pragma unroll
  for (int c = 0; c < 10; ++c) {
    float kv = k[((size_t)bh * TSEQ + cand[c]) * HD + lane];
    sc[c] = wsum(qv * kv);
  }
  float mx = sc[0];
#pragma unroll
  for (int c = 1; c < 10; ++c) mx = fmaxf(mx, sc[c]);
  float e[10], den = 0.f;
#pragma unroll
  for (int c = 0; c < 10; ++c) { e[c] = expf(sc[c] - mx); den += e[c]; }
  float o = 0.f;
#pragma unroll
  for (int c = 0; c < 10; ++c) {
    float w = e[c] / den;
    o += w * v[((size_t)bh * TSEQ + cand[c]) * HD + lane];
  }
  preout[((size_t)b * TSEQ + t) * DM + h * HD + lane] = o;
}

extern "C" void kernel_launch(void* const* d_in, const int* in_sizes, int n_in,
                              void* d_out, int out_size, void* d_ws, size_t ws_size,
                              hipStream_t stream) {
  const float* x  = (const float*)d_in[0];
  const float* Wq = (const float*)d_in[1];
  const float* bq = (const float*)d_in[2];
  const float* Wk = (const float*)d_in[3];
  const float* bk = (const float*)d_in[4];
  const float* Wv = (const float*)d_in[5];
  const float* bv = (const float*)d_in[6];
  const float* Wo = (const float*)d_in[7];
  const float* bo = (const float*)d_in[8];
  float* out = (float*)d_out;

  float* ws = (float*)d_ws;
  const size_t QKV = (size_t)NBH * TSEQ * HD;  // 3145728
  float* qb = ws;
  float* kb = qb + QKV;
  float* vb = kb + QKV;
  float* preout = vb + QKV;
  float* Qp = preout + (size_t)2 * TSEQ * DM;  // 3145728
  float* S  = Qp + (size_t)NH * 32 * HD;       // 24576
  float* u  = S + (size_t)NH * TSEQ * 32;      // 786432
  int* sel  = (int*)(u + (size_t)NH * TSEQ);   // 24576
  int* glob = sel + (size_t)NBH * TSEQ * 6;    // 294912 ints

  qkv_kernel<<<dim3(6, 32, 3), 512, 0, stream>>>(x, Wq, bq, qb, Wk, bk, kb, Wv, bv, vb);
  window_kernel<<<12288, 256, 0, stream>>>(qb, kb, sel);
  qp_kernel<<<96, 256, 0, stream>>>(qb, Qp);
  proto_score_kernel<<<dim3(512, NH), 256, 0, stream>>>(kb, Qp, S, u);
  head_select_kernel<<<NH, 64, 0, stream>>>(u, S, glob);
  attend_kernel<<<12288, 256, 0, stream>>>(qb, kb, vb, sel, glob, preout);
  oproj_kernel<<<dim3(6, 32, 1), 512, 0, stream>>>(preout, Wo, bo, out);
}

// Round 2
// 511.388 us; speedup vs baseline: 1.4685x; 1.4685x over previous
//
#include <hip/hip_runtime.h>
#include <math.h>

#define TSEQ 2048
#define DM   768
#define NH   12
#define HD   64
#define NBH  24

// round(linspace(0, 2047, 32)) — verified against fp32 evaluation (no .5 ties)
__constant__ int c_idxp[32] = {0,66,132,198,264,330,396,462,528,594,660,726,
  792,858,924,990,1057,1123,1189,1255,1321,1387,1453,1519,1585,1651,1717,1783,
  1849,1915,1981,2047};

__device__ __forceinline__ float wsum(float v) {
#pragma unroll
  for (int m = 1; m < 64; m <<= 1) v += __shfl_xor(v, m, 64);
  return v;
}
__device__ __forceinline__ float wmaxr(float v) {
#pragma unroll
  for (int m = 1; m < 64; m <<= 1) v = fmaxf(v, __shfl_xor(v, m, 64));
  return v;
}

// ---------------- GEMM: dst = (X @ W^T + bias) * scale ----------------
// BM=BN=128, BK=16, 512 threads, 8x4 per thread.
// MODE 0: row-major [M,DM] store.  MODE 1: qkv layout store (b*NH+h, t, dd).
template <int MODE>
__device__ __forceinline__ void gemm_body(const float* __restrict__ X,
                                          const float* __restrict__ W,
                                          const float* __restrict__ bias,
                                          float* __restrict__ dst, float scale,
                                          int mblk, int nblk,
                                          float (*As)[132], float (*Bs)[132]) {
  const int tid = threadIdx.x;
  const int tx = tid & 31;       // column group (col = tx*4)
  const int ty = tid >> 5;       // 0..15 (rows ty*4+i and 64+ty*4+i)
  const int lr = tid >> 2;       // staging row 0..127
  const int lc = (tid & 3) * 4;  // staging k offset {0,4,8,12}
  const float* Xp = X + (size_t)(mblk + lr) * DM + lc;
  const float* Wp = W + (size_t)(nblk + lr) * DM + lc;
  float acc[2][4][4] = {};
  for (int k0 = 0; k0 < DM; k0 += 16) {
    float4 a = *(const float4*)(Xp + k0);
    float4 b = *(const float4*)(Wp + k0);
    __syncthreads();
    As[lc + 0][lr] = a.x; As[lc + 1][lr] = a.y; As[lc + 2][lr] = a.z; As[lc + 3][lr] = a.w;
    Bs[lc + 0][lr] = b.x; Bs[lc + 1][lr] = b.y; Bs[lc + 2][lr] = b.z; Bs[lc + 3][lr] = b.w;
    __syncthreads();
#pragma unroll
    for (int kk = 0; kk < 16; ++kk) {
      float4 a0 = *(const float4*)&As[kk][ty * 4];
      float4 a1 = *(const float4*)&As[kk][ty * 4 + 64];
      float4 bb = *(const float4*)&Bs[kk][tx * 4];
      float ar[2][4] = {{a0.x, a0.y, a0.z, a0.w}, {a1.x, a1.y, a1.z, a1.w}};
      float br[4] = {bb.x, bb.y, bb.z, bb.w};
#pragma unroll
      for (int im = 0; im < 2; ++im)
#pragma unroll
        for (int i = 0; i < 4; ++i)
#pragma unroll
          for (int j = 0; j < 4; ++j)
            acc[im][i][j] = fmaf(ar[im][i], br[j], acc[im][i][j]);
    }
  }
  const int col = nblk + tx * 4;
  const float b0 = bias[col + 0], b1 = bias[col + 1];
  const float b2 = bias[col + 2], b3 = bias[col + 3];
#pragma unroll
  for (int im = 0; im < 2; ++im) {
#pragma unroll
    for (int i = 0; i < 4; ++i) {
      int row = mblk + im * 64 + ty * 4 + i;
      float4 o;
      o.x = (acc[im][i][0] + b0) * scale;
      o.y = (acc[im][i][1] + b1) * scale;
      o.z = (acc[im][i][2] + b2) * scale;
      o.w = (acc[im][i][3] + b3) * scale;
      if (MODE == 0) {
        *(float4*)&dst[(size_t)row * DM + col] = o;
      } else {
        int b_ = row >> 11, t = row & (TSEQ - 1);
        int h = col >> 6, dd = col & 63;
        *(float4*)&dst[(((size_t)(b_ * NH + h)) * TSEQ + t) * HD + dd] = o;
      }
    }
  }
}

__global__ __launch_bounds__(512) void qkv_kernel(
    const float* __restrict__ X,
    const float* __restrict__ Wq, const float* __restrict__ bq, float* __restrict__ qd,
    const float* __restrict__ Wk, const float* __restrict__ bk, float* __restrict__ kd,
    const float* __restrict__ Wv, const float* __restrict__ bv, float* __restrict__ vd) {
  __shared__ float As[16][132];
  __shared__ float Bs[16][132];
  int z = blockIdx.z;
  const float* W = (z == 0) ? Wq : (z == 1) ? Wk : Wv;
  const float* bias = (z == 0) ? bq : (z == 1) ? bk : bv;
  float* dst = (z == 0) ? qd : (z == 1) ? kd : vd;
  float scale = (z == 0) ? 0.125f : 1.0f;
  gemm_body<1>(X, W, bias, dst, scale, blockIdx.y * 128, blockIdx.x * 128, As, Bs);
}

__global__ __launch_bounds__(512) void oproj_kernel(
    const float* __restrict__ X, const float* __restrict__ W,
    const float* __restrict__ bias, float* __restrict__ dst) {
  __shared__ float As[16][132];
  __shared__ float Bs[16][132];
  gemm_body<0>(X, W, bias, dst, 1.0f, blockIdx.y * 128, blockIdx.x * 128, As, Bs);
}

// ---------------- window selection: one wave per (bh, t) ----------------
// lane = f*4 + g : fragment f in [0,16), dim-group g in [0,4) (16 dims each).
__global__ __launch_bounds__(256) void window_kernel(
    const float* __restrict__ q, const float* __restrict__ k,
    int* __restrict__ sel) {
  int wid = blockIdx.x * 4 + (threadIdx.x >> 6);
  int lane = threadIdx.x & 63;
  int f = lane >> 2, g = lane & 3;
  int bh = wid >> 11, t = wid & (TSEQ - 1);
  int start = t - 8;
  if (start < 0) start = 0;
  if (start > TSEQ - 16) start = TSEQ - 16;

  const float* qp = q + ((size_t)bh * TSEQ + t) * HD + g * 16;
  const float* kp = k + ((size_t)bh * TSEQ + start + f) * HD + g * 16;
  float qv[16], kn[16];
#pragma unroll
  for (int j = 0; j < 4; ++j) {
    float4 qq = *(const float4*)(qp + j * 4);
    float4 kk = *(const float4*)(kp + j * 4);
    qv[j * 4 + 0] = qq.x; qv[j * 4 + 1] = qq.y; qv[j * 4 + 2] = qq.z; qv[j * 4 + 3] = qq.w;
    kn[j * 4 + 0] = kk.x; kn[j * 4 + 1] = kk.y; kn[j * 4 + 2] = kk.z; kn[j * 4 + 3] = kk.w;
  }
  float sp = 0.f, np = 0.f;
#pragma unroll
  for (int i = 0; i < 16; ++i) { sp = fmaf(qv[i], kn[i], sp); np = fmaf(kn[i], kn[i], np); }
  sp += __shfl_xor(sp, 1, 64); sp += __shfl_xor(sp, 2, 64);
  np += __shfl_xor(np, 1, 64); np += __shfl_xor(np, 2, 64);
  float nrm = fmaxf(sqrtf(np), 1e-6f);
#pragma unroll
  for (int i = 0; i < 16; ++i) kn[i] = kn[i] / nrm;  // match ref: kw / max(norm,eps)

  int dist = start + f - t; if (dist < 0) dist = -dist;
  float tmp = sp + 0.2f * expf(-(float)dist * 0.125f);

  int* selp = sel + ((size_t)bh * TSEQ + t) * 6;
#pragma unroll
  for (int r = 0; r < 6; ++r) {
    // wave argmax over f with first-max (smallest f) tie-break, as jnp.argmax
    float best = tmp; int bj = f;
#pragma unroll
    for (int m = 1; m < 64; m <<= 1) {
      float ov = __shfl_xor(best, m, 64);
      int oi = __shfl_xor(bj, m, 64);
      if (ov > best || (ov == best && oi < bj)) { best = ov; bj = oi; }
    }
    if (lane == 0) selp[r] = start + bj;
    if (r < 5) {
      float cp = 0.f;
      int src = (bj << 2) | g;
#pragma unroll
      for (int i = 0; i < 16; ++i) {
        float knj = __shfl(kn[i], src, 64);
        cp = fmaf(kn[i], knj, cp);
      }
      cp += __shfl_xor(cp, 1, 64); cp += __shfl_xor(cp, 2, 64);
      tmp -= 0.2f * fmaxf(cp, 0.f);  // penalty applied before masking (ref order)
    }
    if (f == bj) tmp = -1e9f;
  }
}

// ---------------- prototype queries Qp[a][p][:] ----------------
__global__ __launch_bounds__(256) void qp_kernel(const float* __restrict__ q,
                                                 float* __restrict__ Qp) {
  int wid = blockIdx.x * 4 + (threadIdx.x >> 6);  // 0..383
  int lane = threadIdx.x & 63;
  int a = wid >> 5, p = wid & 31;
  int t = c_idxp[p];
  float v = 0.5f * (q[((size_t)(2 * a) * TSEQ + t) * HD + lane] +
                    q[((size_t)(2 * a + 1) * TSEQ + t) * HD + lane]);
  float n2 = wsum(v * v);
  float nrm = fmaxf(sqrtf(n2), 1e-6f);
  Qp[((size_t)a * 32 + p) * HD + lane] = v / nrm;
}

// ---------------- S[a][t][p] and u[a][t] ----------------
__global__ __launch_bounds__(256) void proto_score_kernel(
    const float* __restrict__ k, const float* __restrict__ Qp,
    float* __restrict__ S, float* __restrict__ u) {
  int a = blockIdx.y;
  __shared__ float Qs[2048];
  for (int i = threadIdx.x; i < 2048; i += 256) Qs[i] = Qp[(size_t)a * 2048 + i];
  __syncthreads();
  int w = threadIdx.x >> 6, lane = threadIdx.x & 63;
  int t = blockIdx.x * 4 + w;
  float km = 0.5f * (k[((size_t)(2 * a) * TSEQ + t) * HD + lane] +
                     k[((size_t)(2 * a + 1) * TSEQ + t) * HD + lane]);
  float n2 = wsum(km * km);
  float nrm = fmaxf(sqrtf(n2), 1e-6f);
  float kb = km / nrm;
  float sval = 0.f;
#pragma unroll
  for (int p = 0; p < 32; ++p) {
    float dg = wsum(kb * Qs[p * 64 + lane]);
    dg = fmaxf(dg, 0.f);               // relu
    sval = (lane == p) ? dg : sval;    // lane p keeps S_p
  }
  if (lane < 32) S[((size_t)a * TSEQ + t) * 32 + lane] = sval;
  float x = (lane < 32) ? sval : 0.f;
  float mean = wsum(x) / 32.0f;
  float mx = wmaxr((lane < 32) ? sval : -1e30f);
  float cur = (lane < 32) ? sval : -1e30f;
  float topsum = 0.f;
#pragma unroll
  for (int r = 0; r < 6; ++r) {        // top-6 values (remove one instance each)
    float m = wmaxr(cur);
    topsum += m;
    unsigned long long ball = __ballot(cur == m);
    int first = __ffsll(ball) - 1;
    if (lane == first) cur = -1e30f;
  }
  float dev = (lane < 32) ? (sval - mean) : 0.f;
  float sd = sqrtf(wsum(dev * dev) / 31.0f);  // ddof=1
  float uval = ((1.0f * mean + 0.6f * mx) + 0.4f * (topsum / 6.0f)) + 0.2f * sd;
  if (lane == 0) u[(size_t)a * TSEQ + t] = uval;
}

// ---------------- per-head top-12 + greedy facility location ----------------
__global__ void head_select_kernel(const float* __restrict__ u,
                                   const float* __restrict__ S,
                                   int* __restrict__ glob) {
  int a = blockIdx.x;
  int lane = threadIdx.x;  // 64 threads
  float uv[32];
#pragma unroll
  for (int c = 0; c < 32; ++c) uv[c] = u[(size_t)a * TSEQ + c * 64 + lane];
  unsigned removed = 0;
  int tidx = 0;
#pragma unroll
  for (int r = 0; r < 12; ++r) {
    float best = -1e30f; int bidx = 1 << 30;
#pragma unroll
    for (int c = 0; c < 32; ++c) {
      if (!((removed >> c) & 1u)) {
        float vv = uv[c]; int gi = c * 64 + lane;
        if (vv > best || (vv == best && gi < bidx)) { best = vv; bidx = gi; }
      }
    }
#pragma unroll
    for (int mS = 1; mS < 64; mS <<= 1) {
      float ov = __shfl_xor(best, mS, 64);
      int oi = __shfl_xor(bidx, mS, 64);
      if (ov > best || (ov == best && oi < bidx)) { best = ov; bidx = oi; }
    }
    if (lane == (bidx & 63)) removed |= 1u << (bidx >> 6);
    if (lane == r) tidx = bidx;   // lane r remembers top_idx[r]
  }
  float srow[12];
#pragma unroll
  for (int r = 0; r < 12; ++r) {
    int tr = __shfl(tidx, r, 64);
    srow[r] = (lane < 32) ? S[((size_t)a * TSEQ + tr) * 32 + lane] : 0.f;
  }
  float m = 0.f;
  unsigned blocked = 0;
#pragma unroll
  for (int g = 0; g < 4; ++g) {
    float gains[12];
#pragma unroll
    for (int r = 0; r < 12; ++r) {
      float gr = (lane < 32) ? fmaxf(srow[r] - m, 0.f) : 0.f;
      gains[r] = wsum(gr);
    }
    float best = -1e30f; int bj = 0;
#pragma unroll
    for (int r = 0; r < 12; ++r) {
      float vv = ((blocked >> r) & 1u) ? -1e9f : gains[r];
      if (vv > best) { best = vv; bj = r; }  // first-max
    }
    blocked |= 1u << bj;
#pragma unroll
    for (int r = 0; r < 12; ++r) m = (r == bj) ? fmaxf(m, srow[r]) : m;
    int gidx = __shfl(tidx, bj, 64);
    if (lane == 0) glob[a * 4 + g] = gidx;
  }
}

// ---------------- final 10-candidate attention ----------------
__global__ __launch_bounds__(256) void attend_kernel(
    const float* __restrict__ q, const float* __restrict__ k,
    const float* __restrict__ v, const int* __restrict__ sel,
    const int* __restrict__ glob, float* __restrict__ preout) {
  int wid = blockIdx.x * 4 + (threadIdx.x >> 6);
  int lane = threadIdx.x & 63;
  int bh = wid >> 11, t = wid & (TSEQ - 1);
  int h = bh % NH, b = bh / NH;
  float qv = q[((size_t)bh * TSEQ + t) * HD + lane];
  int cand[10];
  const int* selp = sel + ((size_t)bh * TSEQ + t) * 6;
#pragma unroll
  for (int c = 0; c < 6; ++c) cand[c] = selp[c];
#pragma unroll
  for (int c = 0; c < 4; ++c) cand[6 + c] = glob[h * 4 + c];
  float sc[10];
#pragma unroll
  for (int c = 0; c < 10; ++c) {
    float kv = k[((size_t)bh * TSEQ + cand[c]) * HD + lane];
    sc[c] = wsum(qv * kv);
  }
  float mx = sc[0];
#pragma unroll
  for (int c = 1; c < 10; ++c) mx = fmaxf(mx, sc[c]);
  float e[10], den = 0.f;
#pragma unroll
  for (int c = 0; c < 10; ++c) { e[c] = expf(sc[c] - mx); den += e[c]; }
  float o = 0.f;
#pragma unroll
  for (int c = 0; c < 10; ++c) {
    float w = e[c] / den;
    o += w * v[((size_t)bh * TSEQ + cand[c]) * HD + lane];
  }
  preout[((size_t)b * TSEQ + t) * DM + h * HD + lane] = o;
}

extern "C" void kernel_launch(void* const* d_in, const int* in_sizes, int n_in,
                              void* d_out, int out_size, void* d_ws, size_t ws_size,
                              hipStream_t stream) {
  const float* x  = (const float*)d_in[0];
  const float* Wq = (const float*)d_in[1];
  const float* bq = (const float*)d_in[2];
  const float* Wk = (const float*)d_in[3];
  const float* bk = (const float*)d_in[4];
  const float* Wv = (const float*)d_in[5];
  const float* bv = (const float*)d_in[6];
  const float* Wo = (const float*)d_in[7];
  const float* bo = (const float*)d_in[8];
  float* out = (float*)d_out;

  float* ws = (float*)d_ws;
  const size_t QKV = (size_t)NBH * TSEQ * HD;  // 3145728
  float* qb = ws;
  float* kb = qb + QKV;
  float* vb = kb + QKV;
  float* preout = vb + QKV;
  float* Qp = preout + (size_t)2 * TSEQ * DM;  // 3145728
  float* S  = Qp + (size_t)NH * 32 * HD;       // 24576
  float* u  = S + (size_t)NH * TSEQ * 32;      // 786432
  int* sel  = (int*)(u + (size_t)NH * TSEQ);   // 24576
  int* glob = sel + (size_t)NBH * TSEQ * 6;    // 294912 ints

  qkv_kernel<<<dim3(6, 32, 3), 512, 0, stream>>>(x, Wq, bq, qb, Wk, bk, kb, Wv, bv, vb);
  window_kernel<<<12288, 256, 0, stream>>>(qb, kb, sel);
  qp_kernel<<<96, 256, 0, stream>>>(qb, Qp);
  proto_score_kernel<<<dim3(512, NH), 256, 0, stream>>>(kb, Qp, S, u);
  head_select_kernel<<<NH, 64, 0, stream>>>(u, S, glob);
  attend_kernel<<<12288, 256, 0, stream>>>(qb, kb, vb, sel, glob, preout);
  oproj_kernel<<<dim3(6, 32, 1), 512, 0, stream>>>(preout, Wo, bo, out);
}